// Round 6
// baseline (257.701 us; speedup 1.0000x reference)
//
#include <hip/hip_runtime.h>
#include <math.h>

// GraphAttentionBlock: B=1, N=4096, E=256, H=8, D=32, fp32 in/out.
// R6: (1) attn XCD-head pinning (1-D grid, h = bid&7 -> per-XCD working set
// ~2.75MB fits 4MB L2); (2) mask s_load software-pipelined one tile ahead,
// V-frags issued at loop top; (3) pack_mask split into coalesced row-ballot
// + bit-transpose (was 25% cache-line utilization); (4) qkv/out preload all
// A-fragments before the K-loop.

#define NTOK 4096
#define EDIM 256
#define HEADS 8
#define HD 32
#define NSPLIT 4
#define QSCALE 0.17677669529663687f            // 1/sqrt(32)
#define LOG2E 1.4426950408889634f
#define CINIT (-11.541560327111707f)           // -8 * log2(e)

typedef __attribute__((ext_vector_type(8))) short bf16x8;
typedef __attribute__((ext_vector_type(4))) float f32x4;
typedef __attribute__((ext_vector_type(4))) unsigned long long u64x4;

static __device__ inline short f2bf(float f) {          // RNE
    unsigned u = __float_as_uint(f);
    u = (u + 0x7FFFu + ((u >> 16) & 1u)) >> 16;
    return (short)u;
}
// pack two floats to bf16x2 (round-half-up; errors cancel in O/l ratio)
static __device__ inline unsigned pack2bf(float a, float b) {
    unsigned pa = __float_as_uint(a) + 0x8000u;
    unsigned pb = __float_as_uint(b) + 0x8000u;
    return (pa >> 16) | (pb & 0xFFFF0000u);
}
static __device__ inline float exp2_fast(float x) {
    float r;
    asm("v_exp_f32 %0, %1" : "=v"(r) : "v"(x));
    return r;
}
// p = (mask bit for this lane) ? v : 0   -- one VALU op, sgpr-pair mask
static __device__ inline float sel_mask(float v, unsigned long long m) {
    float r;
    asm("v_cndmask_b32 %0, 0, %1, %2" : "=v"(r) : "v"(v), "s"(m));
    return r;
}

// ---- phase 1: coalesced row ballots: rowbits[row*64+kb] bit l = adj[row][kb*64+l]
__global__ __launch_bounds__(256) void pack_rows(
    const int* __restrict__ adj, unsigned long long* __restrict__ rowbits)
{
    const int w = blockIdx.x * 4 + (threadIdx.x >> 6);   // = row*64 + kb
    const int l = threadIdx.x & 63;
    const unsigned long long m = __ballot(adj[(size_t)w * 64 + l] != 0);
    if (l == 0) rowbits[w] = m;
}

// ---- phase 2: bit-transpose into S^T MFMA order --------------------------
// maskT[qb*1024+kt*16+b*4+j] bit l = adj[qb*16+(l&15)][kt*64+b*16+((l>>4)&3)*4+j]
__global__ __launch_bounds__(256) void pack_transpose(
    const unsigned long long* __restrict__ rowbits,
    unsigned long long* __restrict__ maskT)
{
    const int u = blockIdx.x * 4 + (threadIdx.x >> 6);   // (qb, kt)
    const int l = threadIdx.x & 63;
    const int qb = u >> 6, kt = u & 63;
    const unsigned long long w = rowbits[(qb * 16 + (l & 15)) * 64 + kt];
    const int g = (l >> 4) & 3;
    unsigned long long* __restrict__ dst = &maskT[(size_t)qb * 1024 + kt * 16];
#pragma unroll
    for (int b = 0; b < 4; ++b)
#pragma unroll
        for (int j = 0; j < 4; ++j) {
            const unsigned long long mm =
                __ballot(((w >> (b * 16 + g * 4 + j)) & 1ull) != 0);
            if (l == 0) dst[b * 4 + j] = mm;
        }
}

// ---- one-shot fp32 -> bf16 cast of x and the 4 weight matrices -----------
__global__ __launch_bounds__(256) void cast_all(
    const float* __restrict__ x,  const float* __restrict__ Wq,
    const float* __restrict__ Wk, const float* __restrict__ Wv,
    const float* __restrict__ Wo,
    short* __restrict__ xb,  short* __restrict__ wqb,
    short* __restrict__ wkb, short* __restrict__ wvb,
    short* __restrict__ wob)
{
    const int gid = blockIdx.x * 256 + threadIdx.x;
    const int e = gid * 4;
    const float* src; short* dst; int off;
    if (e < NTOK * EDIM) { src = x; dst = xb; off = e; }
    else {
        const int r = e - NTOK * EDIM;
        const int wsel = r >> 16;
        off = r & 65535;
        src = (wsel == 0) ? Wq : (wsel == 1) ? Wk : (wsel == 2) ? Wv : Wo;
        dst = (wsel == 0) ? wqb : (wsel == 1) ? wkb : (wsel == 2) ? wvb : wob;
    }
    float4 v = *(const float4*)&src[off];
    uint2 t;
    t.x = (unsigned short)f2bf(v.x) | ((unsigned)(unsigned short)f2bf(v.y) << 16);
    t.y = (unsigned short)f2bf(v.z) | ((unsigned)(unsigned short)f2bf(v.w) << 16);
    *(uint2*)&dst[off] = t;
}

// ---- QKV projection via MFMA, 16x64 per wave; q/k head-major, v transposed
__global__ __launch_bounds__(256) void qkv_mfma(
    const short* __restrict__ xb,
    const short* __restrict__ Wqb, const short* __restrict__ Wkb,
    const short* __restrict__ Wvb,
    const float* __restrict__ bq, const float* __restrict__ bk,
    const float* __restrict__ bv,
    short* __restrict__ qo, short* __restrict__ ko, short* __restrict__ vto)
{
    const int tid = threadIdx.x;
    const int wv = tid >> 6, lane = tid & 63;
    const int grp = lane >> 4, lcol = lane & 15;
    const int wsel = blockIdx.y >> 2;                  // 0=Q 1=K 2=V
    const int n0 = (blockIdx.y & 3) << 6;
    const int m0 = blockIdx.x * 64 + wv * 16;
    const short* __restrict__ W = (wsel == 0) ? Wqb : (wsel == 1) ? Wkb : Wvb;
    const float* __restrict__ bias = (wsel == 0) ? bq : (wsel == 1) ? bk : bv;

    // preload all A-fragments (x rows) so the k-loop only waits on B
    bf16x8 af[8];
#pragma unroll
    for (int k = 0; k < 8; ++k)
        af[k] = *(const bf16x8*)&xb[(m0 + lcol) * 256 + k * 32 + grp * 8];

    f32x4 acc[4] = {};
#pragma unroll
    for (int k = 0; k < 8; ++k) {
#pragma unroll
        for (int t = 0; t < 4; ++t) {
            const bf16x8 bt =
                *(const bf16x8*)&W[(n0 + t * 16 + lcol) * 256 + k * 32 + grp * 8];
            acc[t] = __builtin_amdgcn_mfma_f32_16x16x32_bf16(af[k], bt, acc[t], 0, 0, 0);
        }
    }
#pragma unroll
    for (int t = 0; t < 4; ++t) {
        const int feat = n0 + t * 16 + lcol;
        const float bval = bias[feat];
        const int h = feat >> 5, d = feat & 31;
        if (wsel == 2) {
            uint2 o;
            o.x = (unsigned short)f2bf(acc[t][0] + bval) |
                  ((unsigned)(unsigned short)f2bf(acc[t][1] + bval) << 16);
            o.y = (unsigned short)f2bf(acc[t][2] + bval) |
                  ((unsigned)(unsigned short)f2bf(acc[t][3] + bval) << 16);
            *(uint2*)&vto[h * (HD * NTOK) + d * NTOK + m0 + grp * 4] = o;
        } else {
            short* __restrict__ out = (wsel == 0) ? qo : ko;
            const float sc = (wsel == 0) ? (QSCALE * LOG2E) : 1.0f;
#pragma unroll
            for (int j = 0; j < 4; ++j)
                out[h * (NTOK * HD) + (m0 + grp * 4 + j) * HD + d] =
                    f2bf((acc[t][j] + bval) * sc);
        }
    }
}

// ---- barrier-free MFMA flash attention (S^T / O^T, XCD-head-pinned) ------
__global__ __launch_bounds__(256) void attn_mfma(
    const short* __restrict__ qg, const short* __restrict__ kg,
    const short* __restrict__ vtg, const unsigned long long* __restrict__ maskT,
    float* __restrict__ o_part, float* __restrict__ l_part)
{
    // 1-D grid, consecutive ids cycle heads -> each XCD pinned to one head
    const int bid = blockIdx.x;
    const int h = bid & 7;
    const int split = (bid >> 3) & 3;
    const int q0 = (bid >> 5) << 6;
    const short* __restrict__ Q  = qg  + h * (NTOK * HD);
    const short* __restrict__ K  = kg  + h * (NTOK * HD);
    const short* __restrict__ Vt = vtg + h * (HD * NTOK);

    __shared__ short P_lds[4][16][76];   // 152B rows: uniform 4-way banking

    const int tid = threadIdx.x;
    const int wv = tid >> 6;
    const int lane = tid & 63;
    const int grp = lane >> 4;
    const int lcol = lane & 15;
    const int q0w = q0 + wv * 16;

    // Q as B-operand: B[n=lcol(qrow)][k=grp*8+j(d)]
    const bf16x8 qfrag = *(const bf16x8*)&Q[(q0w + lcol) * HD + grp * 8];

    const int qb = __builtin_amdgcn_readfirstlane((bid >> 5) * 4 + wv);
    const unsigned long long* __restrict__ mbase = maskT + (size_t)qb * 1024;

    f32x4 ot[2] = {};     // O^T C-layout: row=grp*4+j (d), col=lcol (qrow)
    float lsum = 0.f;

    const int kt_begin = split * (64 / NSPLIT);
    const int kt_end = kt_begin + (64 / NSPLIT);

    bf16x8 kf[4];
#pragma unroll
    for (int b = 0; b < 4; ++b)
        kf[b] = *(const bf16x8*)&K[((kt_begin << 6) + b * 16 + lcol) * HD + grp * 8];
    // mask for first tile (software-pipelined thereafter)
    const u64x4* mp0 = (const u64x4*)(mbase + kt_begin * 16);
    u64x4 wa = mp0[0], wb = mp0[1], wc = mp0[2], wd = mp0[3];

    for (int kt = kt_begin; kt < kt_end; ++kt) {
        const int k0 = kt << 6;
        const int ktn = (kt + 1 < kt_end) ? kt + 1 : kt;

        // V^T fragments issued first (longest time to cover latency)
        bf16x8 vf[4];
#pragma unroll
        for (int c = 0; c < 2; ++c) {
            vf[c * 2 + 0] = *(const bf16x8*)&Vt[(c * 16 + lcol) * NTOK + k0 + grp * 8];
            vf[c * 2 + 1] = *(const bf16x8*)&Vt[(c * 16 + lcol) * NTOK + k0 + 32 + grp * 8];
        }

        // S^T = K Q^T (scaled, minus 8*log2e): row=key_in_blk, col=qrow
        f32x4 s[4];
#pragma unroll
        for (int b = 0; b < 4; ++b)
            s[b] = __builtin_amdgcn_mfma_f32_16x16x32_bf16(
                kf[b], qfrag, (f32x4){CINIT, CINIT, CINIT, CINIT}, 0, 0, 0);

        // prefetch next tile's K fragments
#pragma unroll
        for (int b = 0; b < 4; ++b)
            kf[b] = *(const bf16x8*)&K[((ktn << 6) + b * 16 + lcol) * HD + grp * 8];

        // p = exp2(s') masked; pack j=0..3 (consecutive keys) -> ds_write_b64
#pragma unroll
        for (int b = 0; b < 4; ++b) {
            const u64x4 wj = (b == 0) ? wa : (b == 1) ? wb : (b == 2) ? wc : wd;
            const float p0 = sel_mask(exp2_fast(s[b][0]), wj[0]);
            const float p1 = sel_mask(exp2_fast(s[b][1]), wj[1]);
            const float p2 = sel_mask(exp2_fast(s[b][2]), wj[2]);
            const float p3 = sel_mask(exp2_fast(s[b][3]), wj[3]);
            lsum += (p0 + p1) + (p2 + p3);
            uint2 t;
            t.x = pack2bf(p0, p1);
            t.y = pack2bf(p2, p3);
            *(uint2*)&P_lds[wv][lcol][b * 16 + grp * 4] = t;
        }

        // prefetch next tile's mask words (consumed next iteration)
        {
            const u64x4* mpn = (const u64x4*)(mbase + ktn * 16);
            wa = mpn[0]; wb = mpn[1]; wc = mpn[2]; wd = mpn[3];
        }

        // P as B-operand: B[n=lcol(qrow)][k=grp*8+j(key)] -> row-contiguous
        const uint2 pl0 = *(const uint2*)&P_lds[wv][lcol][grp * 8];
        const uint2 pl1 = *(const uint2*)&P_lds[wv][lcol][grp * 8 + 4];
        const uint2 pl2 = *(const uint2*)&P_lds[wv][lcol][32 + grp * 8];
        const uint2 pl3 = *(const uint2*)&P_lds[wv][lcol][32 + grp * 8 + 4];
        struct { uint2 a, b; } u0 = {pl0, pl1}, u1 = {pl2, pl3};
        const bf16x8 pf0 = __builtin_bit_cast(bf16x8, u0);
        const bf16x8 pf1 = __builtin_bit_cast(bf16x8, u1);

#pragma unroll
        for (int c = 0; c < 2; ++c) {
            ot[c] = __builtin_amdgcn_mfma_f32_16x16x32_bf16(vf[c * 2 + 0], pf0, ot[c], 0, 0, 0);
            ot[c] = __builtin_amdgcn_mfma_f32_16x16x32_bf16(vf[c * 2 + 1], pf1, ot[c], 0, 0, 0);
        }
    }

    // l: sum over the 4 lane-groups holding this qrow's keys
    lsum += __shfl_xor(lsum, 16);
    lsum += __shfl_xor(lsum, 32);

    float* __restrict__ ob = o_part + split * (NTOK * EDIM);
#pragma unroll
    for (int c = 0; c < 2; ++c) {
        float4 st;
        st.x = ot[c][0]; st.y = ot[c][1]; st.z = ot[c][2]; st.w = ot[c][3];
        *(float4*)&ob[(q0w + lcol) * EDIM + h * HD + c * 16 + grp * 4] = st;
    }
    if (grp == 0)
        l_part[split * (NTOK * HEADS) + (q0w + lcol) * HEADS + h] = lsum;
}

// ---- split-K combine + normalize + bf16 cast -----------------------------
__global__ __launch_bounds__(256) void combine_cast(
    const float* __restrict__ o_part, const float* __restrict__ l_part,
    short* __restrict__ ab)
{
    const int gid = blockIdx.x * 256 + threadIdx.x;
    const int row = gid >> 6;
    const int c4 = (gid & 63) << 2;
    const int hh = c4 >> 5;
    float4 a0 = *(const float4*)&o_part[0 * (NTOK * EDIM) + row * EDIM + c4];
    float4 a1 = *(const float4*)&o_part[1 * (NTOK * EDIM) + row * EDIM + c4];
    float4 a2 = *(const float4*)&o_part[2 * (NTOK * EDIM) + row * EDIM + c4];
    float4 a3 = *(const float4*)&o_part[3 * (NTOK * EDIM) + row * EDIM + c4];
    const float l = l_part[0 * (NTOK * HEADS) + row * HEADS + hh]
                  + l_part[1 * (NTOK * HEADS) + row * HEADS + hh]
                  + l_part[2 * (NTOK * HEADS) + row * HEADS + hh]
                  + l_part[3 * (NTOK * HEADS) + row * HEADS + hh];
    const float inv = 1.0f / l;
    const float r0 = (a0.x + a1.x + a2.x + a3.x) * inv;
    const float r1 = (a0.y + a1.y + a2.y + a3.y) * inv;
    const float r2 = (a0.z + a1.z + a2.z + a3.z) * inv;
    const float r3 = (a0.w + a1.w + a2.w + a3.w) * inv;
    uint2 t;
    t.x = (unsigned short)f2bf(r0) | ((unsigned)(unsigned short)f2bf(r1) << 16);
    t.y = (unsigned short)f2bf(r2) | ((unsigned)(unsigned short)f2bf(r3) << 16);
    *(uint2*)&ab[row * EDIM + c4] = t;
}

// ---- output projection via MFMA, 16x64 per wave --------------------------
__global__ __launch_bounds__(256) void out_mfma(
    const short* __restrict__ ab, const short* __restrict__ Wob,
    const float* __restrict__ bo, float* __restrict__ Y)
{
    const int tid = threadIdx.x;
    const int wv = tid >> 6, lane = tid & 63;
    const int grp = lane >> 4, lcol = lane & 15;
    const int n0 = blockIdx.y << 6;
    const int m0 = blockIdx.x * 64 + wv * 16;

    bf16x8 af[8];
#pragma unroll
    for (int k = 0; k < 8; ++k)
        af[k] = *(const bf16x8*)&ab[(m0 + lcol) * 256 + k * 32 + grp * 8];

    f32x4 acc[4] = {};
#pragma unroll
    for (int k = 0; k < 8; ++k) {
#pragma unroll
        for (int t = 0; t < 4; ++t) {
            const bf16x8 bt =
                *(const bf16x8*)&Wob[(n0 + t * 16 + lcol) * 256 + k * 32 + grp * 8];
            acc[t] = __builtin_amdgcn_mfma_f32_16x16x32_bf16(af[k], bt, acc[t], 0, 0, 0);
        }
    }
#pragma unroll
    for (int t = 0; t < 4; ++t) {
        const float bval = bo[n0 + t * 16 + lcol];
#pragma unroll
        for (int j = 0; j < 4; ++j)
            Y[(m0 + grp * 4 + j) * EDIM + n0 + t * 16 + lcol] = acc[t][j] + bval;
    }
}

extern "C" void kernel_launch(void* const* d_in, const int* in_sizes, int n_in,
                              void* d_out, int out_size, void* d_ws, size_t ws_size,
                              hipStream_t stream) {
    (void)in_sizes; (void)n_in; (void)out_size; (void)ws_size;
    const float* x  = (const float*)d_in[0];
    const int*  adj = (const int*)d_in[1];
    const float* Wq = (const float*)d_in[2];
    const float* bq = (const float*)d_in[3];
    const float* Wk = (const float*)d_in[4];
    const float* bk = (const float*)d_in[5];
    const float* Wv = (const float*)d_in[6];
    const float* bv = (const float*)d_in[7];
    const float* Wo = (const float*)d_in[8];
    const float* bo = (const float*)d_in[9];

    char* ws = (char*)d_ws;
    short* x_bf  = (short*)(ws);                        // 2 MB  [N][256]
    short* q_ws  = (short*)(ws + (2u << 20));           // 2 MB  [H][N][32]
    short* k_ws  = (short*)(ws + (4u << 20));           // 2 MB
    short* vt_ws = (short*)(ws + (6u << 20));           // 2 MB  [H][32][N]
    unsigned long long* maskT =
        (unsigned long long*)(ws + (8u << 20));         // 2 MB
    short* a_bf  = (short*)(ws + (10u << 20));          // 2 MB  [N][256]
    short* Wq_bf = (short*)(ws + (12u << 20));          // 128 KB each
    short* Wk_bf = Wq_bf + (EDIM * EDIM);
    short* Wv_bf = Wk_bf + (EDIM * EDIM);
    short* Wo_bf = Wv_bf + (EDIM * EDIM);
    float* l_part = (float*)(ws + (13u << 20));         // 512 KB [4][N][8]
    unsigned long long* rowbits =
        (unsigned long long*)(ws + (14u << 20));        // 2 MB  [N][64]
    float* o_part = (float*)(ws + (16u << 20));         // 16 MB [4][N][256]

    pack_rows<<<dim3(65536), 256, 0, stream>>>(adj, rowbits);
    cast_all<<<dim3(1280), 256, 0, stream>>>(x, Wq, Wk, Wv, Wo,
                                             x_bf, Wq_bf, Wk_bf, Wv_bf, Wo_bf);
    pack_transpose<<<dim3(4096), 256, 0, stream>>>(rowbits, maskT);
    qkv_mfma<<<dim3(64, 12), 256, 0, stream>>>(x_bf, Wq_bf, Wk_bf, Wv_bf,
                                               bq, bk, bv, q_ws, k_ws, vt_ws);
    attn_mfma<<<dim3(64 * HEADS * NSPLIT), 256, 0, stream>>>(
        q_ws, k_ws, vt_ws, maskT, o_part, l_part);
    combine_cast<<<dim3(1024), 256, 0, stream>>>(o_part, l_part, a_bf);
    out_mfma<<<dim3(64, 4), 256, 0, stream>>>(a_bf, Wo_bf, bo, (float*)d_out);
}

// Round 8
// 229.289 us; speedup vs baseline: 1.1239x; 1.1239x over previous
//
#include <hip/hip_runtime.h>
#include <math.h>

// GraphAttentionBlock: B=1, N=4096, E=256, H=8, D=32, fp32 in/out.
// R8: R7's 2-tile-ILP attention with two NaN fixes: (1) exp via __expf
// (compiler-visible v_mul+v_exp -> hazard recognizer inserts trans-op wait
// states; raw asm v_exp_f32 was opaque), (2) no __launch_bounds__ min-waves
// (R7's 128-VGPR cap forced spills on a ~150-reg live set). Q scale back to
// 1/sqrt(D) (log2e unfolds into __expf), C-init back to -8.0.

#define NTOK 4096
#define EDIM 256
#define HEADS 8
#define HD 32
#define NSPLIT 2
#define QSCALE 0.17677669529663687f            // 1/sqrt(32)
#define CINIT (-8.0f)                          // exp shift, folded into MFMA C

typedef __attribute__((ext_vector_type(8))) short bf16x8;
typedef __attribute__((ext_vector_type(4))) float f32x4;
typedef __attribute__((ext_vector_type(4))) unsigned long long u64x4;

static __device__ inline short f2bf(float f) {          // RNE
    unsigned u = __float_as_uint(f);
    u = (u + 0x7FFFu + ((u >> 16) & 1u)) >> 16;
    return (short)u;
}
// pack two floats to bf16x2 (round-half-up; errors cancel in O/l ratio)
static __device__ inline unsigned pack2bf(float a, float b) {
    unsigned pa = __float_as_uint(a) + 0x8000u;
    unsigned pb = __float_as_uint(b) + 0x8000u;
    return (pa >> 16) | (pb & 0xFFFF0000u);
}
// p = (mask bit for this lane) ? v : 0   -- one VALU op, sgpr-pair mask
// (v_cndmask is a basic VALU op: no trans-op hazard, safe as opaque asm)
static __device__ inline float sel_mask(float v, unsigned long long m) {
    float r;
    asm("v_cndmask_b32 %0, 0, %1, %2" : "=v"(r) : "v"(v), "s"(m));
    return r;
}

// ---- prep: adjacency -> S^T bitmask (blocks 0..16383) + bf16 casts (rest) -
// maskT[qb*1024+kt*16+b*4+j] bit l = adj[qb*16+(l&15)][kt*64+b*16+((l>>4)&3)*4+j]
__global__ __launch_bounds__(256) void prep(
    const int* __restrict__ adj, unsigned long long* __restrict__ maskT,
    const float* __restrict__ x,  const float* __restrict__ Wq,
    const float* __restrict__ Wk, const float* __restrict__ Wv,
    const float* __restrict__ Wo,
    short* __restrict__ xb,  short* __restrict__ wqb,
    short* __restrict__ wkb, short* __restrict__ wvb,
    short* __restrict__ wob)
{
    const int bid = blockIdx.x;
    if (bid < 16384) {
        const int w = bid * 4 + (threadIdx.x >> 6);  // (qb,kt,b)
        const int l = threadIdx.x & 63;
        const int qb = w >> 8;
        const int kt = (w >> 2) & 63;
        const int b = w & 3;
        const int row = qb * 16 + (l & 15);
        const int col = kt * 64 + b * 16 + ((l >> 4) & 3) * 4;
        const int4 av = *(const int4*)&adj[row * NTOK + col];
        const unsigned long long m0 = __ballot(av.x != 0);
        const unsigned long long m1 = __ballot(av.y != 0);
        const unsigned long long m2 = __ballot(av.z != 0);
        const unsigned long long m3 = __ballot(av.w != 0);
        if (l == 0) {
            unsigned long long* dst = &maskT[(size_t)w * 4];
            dst[0] = m0; dst[1] = m1; dst[2] = m2; dst[3] = m3;
        }
    } else {
        const int gid = (bid - 16384) * 256 + threadIdx.x;
        const int e = gid * 4;
        const float* src; short* dst; int off;
        if (e < NTOK * EDIM) { src = x; dst = xb; off = e; }
        else {
            const int r = e - NTOK * EDIM;
            const int wsel = r >> 16;
            off = r & 65535;
            src = (wsel == 0) ? Wq : (wsel == 1) ? Wk : (wsel == 2) ? Wv : Wo;
            dst = (wsel == 0) ? wqb : (wsel == 1) ? wkb : (wsel == 2) ? wvb : wob;
        }
        float4 v = *(const float4*)&src[off];
        uint2 t;
        t.x = (unsigned short)f2bf(v.x) | ((unsigned)(unsigned short)f2bf(v.y) << 16);
        t.y = (unsigned short)f2bf(v.z) | ((unsigned)(unsigned short)f2bf(v.w) << 16);
        *(uint2*)&dst[off] = t;
    }
}

// ---- QKV projection via MFMA, 16x64 per wave; q/k head-major, v transposed
__global__ __launch_bounds__(256) void qkv_mfma(
    const short* __restrict__ xb,
    const short* __restrict__ Wqb, const short* __restrict__ Wkb,
    const short* __restrict__ Wvb,
    const float* __restrict__ bq, const float* __restrict__ bk,
    const float* __restrict__ bv,
    short* __restrict__ qo, short* __restrict__ ko, short* __restrict__ vto)
{
    const int tid = threadIdx.x;
    const int wv = tid >> 6, lane = tid & 63;
    const int grp = lane >> 4, lcol = lane & 15;
    const int wsel = blockIdx.y >> 2;                  // 0=Q 1=K 2=V
    const int n0 = (blockIdx.y & 3) << 6;
    const int m0 = blockIdx.x * 64 + wv * 16;
    const short* __restrict__ W = (wsel == 0) ? Wqb : (wsel == 1) ? Wkb : Wvb;
    const float* __restrict__ bias = (wsel == 0) ? bq : (wsel == 1) ? bk : bv;

    bf16x8 af[8];
#pragma unroll
    for (int k = 0; k < 8; ++k)
        af[k] = *(const bf16x8*)&xb[(m0 + lcol) * 256 + k * 32 + grp * 8];

    f32x4 acc[4] = {};
#pragma unroll
    for (int k = 0; k < 8; ++k) {
#pragma unroll
        for (int t = 0; t < 4; ++t) {
            const bf16x8 bt =
                *(const bf16x8*)&W[(n0 + t * 16 + lcol) * 256 + k * 32 + grp * 8];
            acc[t] = __builtin_amdgcn_mfma_f32_16x16x32_bf16(af[k], bt, acc[t], 0, 0, 0);
        }
    }
#pragma unroll
    for (int t = 0; t < 4; ++t) {
        const int feat = n0 + t * 16 + lcol;
        const float bval = bias[feat];
        const int h = feat >> 5, d = feat & 31;
        if (wsel == 2) {
            uint2 o;
            o.x = (unsigned short)f2bf(acc[t][0] + bval) |
                  ((unsigned)(unsigned short)f2bf(acc[t][1] + bval) << 16);
            o.y = (unsigned short)f2bf(acc[t][2] + bval) |
                  ((unsigned)(unsigned short)f2bf(acc[t][3] + bval) << 16);
            *(uint2*)&vto[h * (HD * NTOK) + d * NTOK + m0 + grp * 4] = o;
        } else {
            short* __restrict__ out = (wsel == 0) ? qo : ko;
            const float sc = (wsel == 0) ? QSCALE : 1.0f;  // 1/sqrt(D) into Q
#pragma unroll
            for (int j = 0; j < 4; ++j)
                out[h * (NTOK * HD) + (m0 + grp * 4 + j) * HD + d] =
                    f2bf((acc[t][j] + bval) * sc);
        }
    }
}

// ---- barrier-free MFMA flash attention, 2 kt tiles in flight per wave ----
__global__ __launch_bounds__(256) void attn_mfma(
    const short* __restrict__ qg, const short* __restrict__ kg,
    const short* __restrict__ vtg, const unsigned long long* __restrict__ maskT,
    float* __restrict__ o_part, float* __restrict__ l_part)
{
    const int h = blockIdx.y;
    const int split = blockIdx.z;
    const int q0 = blockIdx.x << 6;
    const short* __restrict__ Q  = qg  + h * (NTOK * HD);
    const short* __restrict__ K  = kg  + h * (NTOK * HD);
    const short* __restrict__ Vt = vtg + h * (HD * NTOK);

    // two independent P^T regions (one per in-flight tile); 152B rows
    __shared__ short P_lds[2][4][16][76];

    const int tid = threadIdx.x;
    const int wv = tid >> 6;
    const int lane = tid & 63;
    const int grp = lane >> 4;
    const int lcol = lane & 15;
    const int q0w = q0 + wv * 16;

    // Q as B-operand: B[n=lcol(qrow)][k=grp*8+j(d)]
    const bf16x8 qfrag = *(const bf16x8*)&Q[(q0w + lcol) * HD + grp * 8];

    const int qb = __builtin_amdgcn_readfirstlane(blockIdx.x * 4 + wv);
    const unsigned long long* __restrict__ mbase = maskT + (size_t)qb * 1024;

    f32x4 ot[2] = {};     // O^T C-layout: row=grp*4+j (d), col=lcol (qrow)
    float lsum = 0.f;

    const int kt_begin = split * (64 / NSPLIT);
    const int kt_end = kt_begin + (64 / NSPLIT);

    // K fragments for the first pair (prefetched across iterations)
    bf16x8 kfa[4], kfb[4];
#pragma unroll
    for (int b = 0; b < 4; ++b) {
        kfa[b] = *(const bf16x8*)&K[((kt_begin << 6) + b * 16 + lcol) * HD + grp * 8];
        kfb[b] = *(const bf16x8*)&K[(((kt_begin + 1) << 6) + b * 16 + lcol) * HD + grp * 8];
    }

    for (int kt = kt_begin; kt < kt_end; kt += 2) {
        const int k0a = kt << 6, k0b = (kt + 1) << 6;

        // mask words for both tiles: one contiguous 256 B scalar region
        const u64x4* mp = (const u64x4*)(mbase + kt * 16);
        const u64x4 wA[4] = {mp[0], mp[1], mp[2], mp[3]};
        const u64x4 wB[4] = {mp[4], mp[5], mp[6], mp[7]};

        // V^T fragments for both tiles (consumed last -> max latency cover)
        bf16x8 vfa[4], vfb[4];
#pragma unroll
        for (int c = 0; c < 2; ++c) {
            vfa[c * 2 + 0] = *(const bf16x8*)&Vt[(c * 16 + lcol) * NTOK + k0a + grp * 8];
            vfa[c * 2 + 1] = *(const bf16x8*)&Vt[(c * 16 + lcol) * NTOK + k0a + 32 + grp * 8];
            vfb[c * 2 + 0] = *(const bf16x8*)&Vt[(c * 16 + lcol) * NTOK + k0b + grp * 8];
            vfb[c * 2 + 1] = *(const bf16x8*)&Vt[(c * 16 + lcol) * NTOK + k0b + 32 + grp * 8];
        }

        // S^T for both tiles (8 MFMA, two independent chains)
        f32x4 sa[4], sb[4];
#pragma unroll
        for (int b = 0; b < 4; ++b)
            sa[b] = __builtin_amdgcn_mfma_f32_16x16x32_bf16(
                kfa[b], qfrag, (f32x4){CINIT, CINIT, CINIT, CINIT}, 0, 0, 0);
#pragma unroll
        for (int b = 0; b < 4; ++b)
            sb[b] = __builtin_amdgcn_mfma_f32_16x16x32_bf16(
                kfb[b], qfrag, (f32x4){CINIT, CINIT, CINIT, CINIT}, 0, 0, 0);

        // prefetch next pair's K fragments
        const int ktn = (kt + 2 < kt_end) ? kt + 2 : kt;
#pragma unroll
        for (int b = 0; b < 4; ++b) {
            kfa[b] = *(const bf16x8*)&K[((ktn << 6) + b * 16 + lcol) * HD + grp * 8];
            kfb[b] = *(const bf16x8*)&K[(((ktn + 1) << 6) + b * 16 + lcol) * HD + grp * 8];
        }

        // exp/pack tile A -> region 0, tile B -> region 1 (__expf: compiler
        // sees the trans op and inserts required wait states)
#pragma unroll
        for (int b = 0; b < 4; ++b) {
            const float p0 = sel_mask(__expf(sa[b][0]), wA[b][0]);
            const float p1 = sel_mask(__expf(sa[b][1]), wA[b][1]);
            const float p2 = sel_mask(__expf(sa[b][2]), wA[b][2]);
            const float p3 = sel_mask(__expf(sa[b][3]), wA[b][3]);
            lsum += (p0 + p1) + (p2 + p3);
            uint2 t;
            t.x = pack2bf(p0, p1);
            t.y = pack2bf(p2, p3);
            *(uint2*)&P_lds[0][wv][lcol][b * 16 + grp * 4] = t;
        }
#pragma unroll
        for (int b = 0; b < 4; ++b) {
            const float p0 = sel_mask(__expf(sb[b][0]), wB[b][0]);
            const float p1 = sel_mask(__expf(sb[b][1]), wB[b][1]);
            const float p2 = sel_mask(__expf(sb[b][2]), wB[b][2]);
            const float p3 = sel_mask(__expf(sb[b][3]), wB[b][3]);
            lsum += (p0 + p1) + (p2 + p3);
            uint2 t;
            t.x = pack2bf(p0, p1);
            t.y = pack2bf(p2, p3);
            *(uint2*)&P_lds[1][wv][lcol][b * 16 + grp * 4] = t;
        }

        // P as B-operand (row-contiguous b64 pairs) + PV MFMAs
        const uint2 a0 = *(const uint2*)&P_lds[0][wv][lcol][grp * 8];
        const uint2 a1 = *(const uint2*)&P_lds[0][wv][lcol][grp * 8 + 4];
        const uint2 a2 = *(const uint2*)&P_lds[0][wv][lcol][32 + grp * 8];
        const uint2 a3 = *(const uint2*)&P_lds[0][wv][lcol][32 + grp * 8 + 4];
        const uint2 b0 = *(const uint2*)&P_lds[1][wv][lcol][grp * 8];
        const uint2 b1 = *(const uint2*)&P_lds[1][wv][lcol][grp * 8 + 4];
        const uint2 b2 = *(const uint2*)&P_lds[1][wv][lcol][32 + grp * 8];
        const uint2 b3 = *(const uint2*)&P_lds[1][wv][lcol][32 + grp * 8 + 4];
        struct { uint2 a, b; } ua0 = {a0, a1}, ua1 = {a2, a3},
                               ub0 = {b0, b1}, ub1 = {b2, b3};
        const bf16x8 pfa0 = __builtin_bit_cast(bf16x8, ua0);
        const bf16x8 pfa1 = __builtin_bit_cast(bf16x8, ua1);
        const bf16x8 pfb0 = __builtin_bit_cast(bf16x8, ub0);
        const bf16x8 pfb1 = __builtin_bit_cast(bf16x8, ub1);

#pragma unroll
        for (int c = 0; c < 2; ++c) {
            ot[c] = __builtin_amdgcn_mfma_f32_16x16x32_bf16(vfa[c * 2 + 0], pfa0, ot[c], 0, 0, 0);
            ot[c] = __builtin_amdgcn_mfma_f32_16x16x32_bf16(vfa[c * 2 + 1], pfa1, ot[c], 0, 0, 0);
            ot[c] = __builtin_amdgcn_mfma_f32_16x16x32_bf16(vfb[c * 2 + 0], pfb0, ot[c], 0, 0, 0);
            ot[c] = __builtin_amdgcn_mfma_f32_16x16x32_bf16(vfb[c * 2 + 1], pfb1, ot[c], 0, 0, 0);
        }
    }

    // l: sum over the 4 lane-groups holding this qrow's keys
    lsum += __shfl_xor(lsum, 16);
    lsum += __shfl_xor(lsum, 32);

    float* __restrict__ ob = o_part + split * (NTOK * EDIM);
#pragma unroll
    for (int c = 0; c < 2; ++c) {
        float4 st;
        st.x = ot[c][0]; st.y = ot[c][1]; st.z = ot[c][2]; st.w = ot[c][3];
        *(float4*)&ob[(q0w + lcol) * EDIM + h * HD + c * 16 + grp * 4] = st;
    }
    if (grp == 0)
        l_part[split * (NTOK * HEADS) + (q0w + lcol) * HEADS + h] = lsum;
}

// ---- split-K combine + normalize + bf16 cast -----------------------------
__global__ __launch_bounds__(256) void combine_cast(
    const float* __restrict__ o_part, const float* __restrict__ l_part,
    short* __restrict__ ab)
{
    const int gid = blockIdx.x * 256 + threadIdx.x;
    const int row = gid >> 6;
    const int c4 = (gid & 63) << 2;
    const int hh = c4 >> 5;
    float4 a0 = *(const float4*)&o_part[0 * (NTOK * EDIM) + row * EDIM + c4];
    float4 a1 = *(const float4*)&o_part[1 * (NTOK * EDIM) + row * EDIM + c4];
    const float l = l_part[0 * (NTOK * HEADS) + row * HEADS + hh]
                  + l_part[1 * (NTOK * HEADS) + row * HEADS + hh];
    const float inv = 1.0f / l;
    const float r0 = (a0.x + a1.x) * inv;
    const float r1 = (a0.y + a1.y) * inv;
    const float r2 = (a0.z + a1.z) * inv;
    const float r3 = (a0.w + a1.w) * inv;
    uint2 t;
    t.x = (unsigned short)f2bf(r0) | ((unsigned)(unsigned short)f2bf(r1) << 16);
    t.y = (unsigned short)f2bf(r2) | ((unsigned)(unsigned short)f2bf(r3) << 16);
    *(uint2*)&ab[row * EDIM + c4] = t;
}

// ---- output projection via MFMA, 16x64 per wave --------------------------
__global__ __launch_bounds__(256) void out_mfma(
    const short* __restrict__ ab, const short* __restrict__ Wob,
    const float* __restrict__ bo, float* __restrict__ Y)
{
    const int tid = threadIdx.x;
    const int wv = tid >> 6, lane = tid & 63;
    const int grp = lane >> 4, lcol = lane & 15;
    const int n0 = blockIdx.y << 6;
    const int m0 = blockIdx.x * 64 + wv * 16;

    bf16x8 af[8];
#pragma unroll
    for (int k = 0; k < 8; ++k)
        af[k] = *(const bf16x8*)&ab[(m0 + lcol) * 256 + k * 32 + grp * 8];

    f32x4 acc[4] = {};
#pragma unroll
    for (int k = 0; k < 8; ++k) {
#pragma unroll
        for (int t = 0; t < 4; ++t) {
            const bf16x8 bt =
                *(const bf16x8*)&Wob[(n0 + t * 16 + lcol) * 256 + k * 32 + grp * 8];
            acc[t] = __builtin_amdgcn_mfma_f32_16x16x32_bf16(af[k], bt, acc[t], 0, 0, 0);
        }
    }
#pragma unroll
    for (int t = 0; t < 4; ++t) {
        const float bval = bo[n0 + t * 16 + lcol];
#pragma unroll
        for (int j = 0; j < 4; ++j)
            Y[(m0 + grp * 4 + j) * EDIM + n0 + t * 16 + lcol] = acc[t][j] + bval;
    }
}

extern "C" void kernel_launch(void* const* d_in, const int* in_sizes, int n_in,
                              void* d_out, int out_size, void* d_ws, size_t ws_size,
                              hipStream_t stream) {
    (void)in_sizes; (void)n_in; (void)out_size; (void)ws_size;
    const float* x  = (const float*)d_in[0];
    const int*  adj = (const int*)d_in[1];
    const float* Wq = (const float*)d_in[2];
    const float* bq = (const float*)d_in[3];
    const float* Wk = (const float*)d_in[4];
    const float* bk = (const float*)d_in[5];
    const float* Wv = (const float*)d_in[6];
    const float* bv = (const float*)d_in[7];
    const float* Wo = (const float*)d_in[8];
    const float* bo = (const float*)d_in[9];

    char* ws = (char*)d_ws;
    short* x_bf  = (short*)(ws);                        // 2 MB  [N][256]
    short* q_ws  = (short*)(ws + (2u << 20));           // 2 MB  [H][N][32]
    short* k_ws  = (short*)(ws + (4u << 20));           // 2 MB
    short* vt_ws = (short*)(ws + (6u << 20));           // 2 MB  [H][32][N]
    unsigned long long* maskT =
        (unsigned long long*)(ws + (8u << 20));         // 2 MB
    short* a_bf  = (short*)(ws + (10u << 20));          // 2 MB  [N][256]
    short* Wq_bf = (short*)(ws + (12u << 20));          // 128 KB each
    short* Wk_bf = Wq_bf + (EDIM * EDIM);
    short* Wv_bf = Wk_bf + (EDIM * EDIM);
    short* Wo_bf = Wv_bf + (EDIM * EDIM);
    float* l_part = (float*)(ws + (13u << 20));         // 256 KB [2][N][8]
    float* o_part = (float*)(ws + (16u << 20));         // 8 MB   [2][N][256]

    prep<<<dim3(16384 + 1280), 256, 0, stream>>>(
        adj, maskT, x, Wq, Wk, Wv, Wo, x_bf, Wq_bf, Wk_bf, Wv_bf, Wo_bf);
    qkv_mfma<<<dim3(64, 12), 256, 0, stream>>>(x_bf, Wq_bf, Wk_bf, Wv_bf,
                                               bq, bk, bv, q_ws, k_ws, vt_ws);
    attn_mfma<<<dim3(64, HEADS, NSPLIT), 256, 0, stream>>>(
        q_ws, k_ws, vt_ws, maskT, o_part, l_part);
    combine_cast<<<dim3(1024), 256, 0, stream>>>(o_part, l_part, a_bf);
    out_mfma<<<dim3(64, 4), 256, 0, stream>>>(a_bf, Wo_bf, bo, (float*)d_out);
}